// Round 1
// baseline (230.616 us; speedup 1.0000x reference)
//
#include <hip/hip_runtime.h>
#include <hip/hip_bf16.h>

// DynamicPatching: B=32, C=64, T=8192, S=64 segments per batch.
// out[b,s,c,p] = (p < end[b,s]-start[b,s]) ? tensor[b,c,start[b,s]+p] : 0
// Output shape (B, S, C, max_length), float32.

#define DP_B 32
#define DP_C 64
#define DP_T 8192
#define DP_S 64

__global__ __launch_bounds__(256) void DynamicPatching_kernel(
    const float* __restrict__ tensor,     // (B, C, T)
    const int* __restrict__ change_points, // (B, S+1)
    float* __restrict__ out,              // (B, S, C, max_len)
    int max_len) {
  const int c  = blockIdx.x;          // channel
  const int bs = blockIdx.y;          // b*S + s
  const int b  = bs >> 6;             // /S (S=64)
  const int s  = bs & 63;             // %S

  const int start = change_points[b * (DP_S + 1) + s];
  const int end   = change_points[b * (DP_S + 1) + s + 1];
  const int len   = end - start;

  const float* __restrict__ src =
      tensor + ((size_t)b * DP_C + c) * DP_T + start;
  float* __restrict__ dst =
      out + ((size_t)bs * DP_C + c) * (size_t)max_len;

  for (int p = threadIdx.x; p < max_len; p += blockDim.x) {
    dst[p] = (p < len) ? src[p] : 0.0f;
  }
}

extern "C" void kernel_launch(void* const* d_in, const int* in_sizes, int n_in,
                              void* d_out, int out_size, void* d_ws, size_t ws_size,
                              hipStream_t stream) {
  const float* tensor = (const float*)d_in[0];
  const int* change_points = (const int*)d_in[1];
  // max_length is also d_in[2] (scalar), but derive it from out_size so we
  // don't need a device->host read: out_size = B*S*C*max_len.
  const int max_len = out_size / (DP_B * DP_S * DP_C);
  float* out = (float*)d_out;

  dim3 grid(DP_C, DP_B * DP_S);
  dim3 block(256);
  DynamicPatching_kernel<<<grid, block, 0, stream>>>(tensor, change_points, out,
                                                     max_len);
}

// Round 2
// 191.532 us; speedup vs baseline: 1.2041x; 1.2041x over previous
//
#include <hip/hip_runtime.h>
#include <hip/hip_bf16.h>

// DynamicPatching: B=32, C=64, T=8192, S=64 segments per batch.
// out[b,s,c,p] = (p < end[b,s]-start[b,s]) ? tensor[b,c,start[b,s]+p] : 0
// Output shape (B, S, C, max_length) float32. Measured max_length == 256.
//
// R1 post-mortem: 131k tiny blocks (1 elem/thread) -> latency-bound, 1.7 TB/s.
// R2: one block per (b,s), float4 stores (dst 16B-aligned), clamped loads
// (mirrors reference's min(idx, T-1)) so loads are unconditional, unroll x4.

#define DP_B 32
#define DP_C 64
#define DP_T 8192
#define DP_S 64

// Fast path: max_len known at compile time (L % 4 == 0 required).
template <int L>
__global__ __launch_bounds__(256) void dp_kernel_fixed(
    const float* __restrict__ tensor,      // (B, C, T)
    const int* __restrict__ change_points, // (B, S+1)
    float* __restrict__ out) {             // (B, S, C, L)
  const int bs = blockIdx.x;  // b*S + s
  const int b = bs >> 6;      // S == 64
  const int start = change_points[b * (DP_S + 1) + (bs & 63)];
  const int len = change_points[b * (DP_S + 1) + (bs & 63) + 1] - start;

  const float* __restrict__ bbase = tensor + (size_t)b * DP_C * DP_T;
  float* __restrict__ dst = out + (size_t)bs * DP_C * L;

  constexpr int NV = DP_C * L / 4;  // float4 units per block tile
#pragma unroll 4
  for (int v = threadIdx.x; v < NV; v += 256) {
    const int c = v / (L / 4);
    const int p = (v % (L / 4)) * 4;
    const float* __restrict__ row = bbase + (size_t)c * DP_T;
    float4 val;
    {
      int q = start + p + 0; q = q < DP_T ? q : DP_T - 1;
      float t = row[q]; val.x = (p + 0 < len) ? t : 0.0f;
    }
    {
      int q = start + p + 1; q = q < DP_T ? q : DP_T - 1;
      float t = row[q]; val.y = (p + 1 < len) ? t : 0.0f;
    }
    {
      int q = start + p + 2; q = q < DP_T ? q : DP_T - 1;
      float t = row[q]; val.z = (p + 2 < len) ? t : 0.0f;
    }
    {
      int q = start + p + 3; q = q < DP_T ? q : DP_T - 1;
      float t = row[q]; val.w = (p + 3 < len) ? t : 0.0f;
    }
    *(float4*)(dst + v * 4) = val;
  }
}

// Generic fallback (any max_len): scalar, one block per (b,s,c) row.
__global__ __launch_bounds__(256) void dp_kernel_generic(
    const float* __restrict__ tensor,
    const int* __restrict__ change_points,
    float* __restrict__ out, int max_len) {
  const int c = blockIdx.x;
  const int bs = blockIdx.y;
  const int b = bs >> 6;
  const int s = bs & 63;
  const int start = change_points[b * (DP_S + 1) + s];
  const int len = change_points[b * (DP_S + 1) + s + 1] - start;
  const float* __restrict__ src = tensor + ((size_t)b * DP_C + c) * DP_T;
  float* __restrict__ dst = out + ((size_t)bs * DP_C + c) * (size_t)max_len;
  for (int p = threadIdx.x; p < max_len; p += blockDim.x) {
    int q = start + p; q = q < DP_T ? q : DP_T - 1;
    float t = src[q];
    dst[p] = (p < len) ? t : 0.0f;
  }
}

extern "C" void kernel_launch(void* const* d_in, const int* in_sizes, int n_in,
                              void* d_out, int out_size, void* d_ws, size_t ws_size,
                              hipStream_t stream) {
  const float* tensor = (const float*)d_in[0];
  const int* change_points = (const int*)d_in[1];
  const int max_len = out_size / (DP_B * DP_S * DP_C);
  float* out = (float*)d_out;

  if (max_len == 256) {
    dp_kernel_fixed<256><<<dim3(DP_B * DP_S), dim3(256), 0, stream>>>(
        tensor, change_points, out);
  } else {
    dp_kernel_generic<<<dim3(DP_C, DP_B * DP_S), dim3(256), 0, stream>>>(
        tensor, change_points, out, max_len);
  }
}